// Round 3
// baseline (373.465 us; speedup 1.0000x reference)
//
#include <hip/hip_runtime.h>
#include <stdint.h>

#define EMB_DIM 192      // 3 coords * 32 freqs * 2 (sin,cos)
#define KIN 384
#define CDIM 32
#define TDIM 4
#define N_Y 50000
#define N_X 32768
#define KNBR 8
#define ECNT (N_X*KNBR)  // 262144

// LDS strides chosen so word-stride is ODD (134/2=67, 262/2=131 words) -> spread banks
#define H1S 134
#define H2S 262
#define KS  33

typedef __attribute__((ext_vector_type(8))) short bf16x8;
typedef __attribute__((ext_vector_type(4))) float f32x4;

static __device__ __forceinline__ short f2bf(float f){
  unsigned u = __float_as_uint(f);
  return (short)((u + 0x7FFFu) >> 16);      // round-half-down (2 ops; |err| <= RNE+eps)
}
static __device__ __forceinline__ float geluf(float x){
  // jax.nn.gelu tanh-approx: x * sigmoid(2*0.79788456*x*(1+0.044715x^2))
  float x2 = x * x;
  float u  = __builtin_fmaf(0.044715f, x2, 1.0f);
  float p  = x * -1.5957691216057308f;      // -2*0.7978845608 folded
  float e  = __expf(p * u);                 // exp(-2t)
  return x * __builtin_amdgcn_rcpf(1.0f + e);
}

// ---- embeddings for y (rows 0..N_Y-1) and x (rows N_Y..): one launch ----
__global__ __launch_bounds__(256) void embed_all(const float* __restrict__ ypts,
                                                 const float* __restrict__ xpts,
                                                 short* __restrict__ emb){
  int id = blockIdx.x * 256 + threadIdx.x;
  int total = (N_Y + N_X) * 96;             // rows * (3 coords * 32 freqs)
  if (id >= total) return;
  int row = id / 96;
  int q = id - row * 96;
  int d = q >> 5, i = q & 31;
  float p = (row < N_Y) ? ypts[row * 3 + d] : xpts[(row - N_Y) * 3 + d];
  float f = __expf(-9.210340371976184f * (float)i * (1.0f / 32.0f)); // (1e-4)^(i/32)
  float s, c;
  __sincosf(p * f, &s, &c);
  unsigned u0 = __float_as_uint(s), u1 = __float_as_uint(c);
  unsigned pack = ((u0 + 0x7FFFu) >> 16) | (((u1 + 0x7FFFu) >> 16) << 16);
  *(unsigned*)&emb[(size_t)row * EMB_DIM + d * 64 + 2 * i] = pack;
}

// ---- all four W (K,N) fp32 -> W^T (N,K) bf16 in one launch ----
__global__ __launch_bounds__(256) void transpose_all(
    const float* __restrict__ W0, const float* __restrict__ W1,
    const float* __restrict__ W2, const float* __restrict__ W3,
    short* __restrict__ w0t, short* __restrict__ w1t,
    short* __restrict__ w2t, short* __restrict__ w3t){
  int id = blockIdx.x * 256 + threadIdx.x;
  const float* src; short* dst; int K, N, loc;
  if      (id < 49152)  { src = W0; dst = w0t; K = 384; N = 128; loc = id; }
  else if (id < 81920)  { src = W1; dst = w1t; K = 128; N = 256; loc = id - 49152; }
  else if (id < 114688) { src = W2; dst = w2t; K = 256; N = 128; loc = id - 81920; }
  else if (id < 118784) { src = W3; dst = w3t; K = 128; N = 32;  loc = id - 114688; }
  else return;
  int n = loc / K, k = loc - n * K;
  dst[n * K + k] = f2bf(src[k * N + n]);
}

// ---- fused: gather-MLP (4 layers, MFMA) + K=8 segment reduce, per 64-edge block ----
__global__ __launch_bounds__(256, 3) void fused_mlp(
    const short* __restrict__ yemb, const short* __restrict__ xemb,
    const int* __restrict__ nidx, const float* __restrict__ f_y,
    const short* __restrict__ w0t, const float* __restrict__ b0,
    const short* __restrict__ w1t, const float* __restrict__ b1,
    const short* __restrict__ w2t, const float* __restrict__ b2,
    const short* __restrict__ w3t, const float* __restrict__ b3,
    float* __restrict__ out)
{
  // LDS: idx[64] | h1 64xH1S bf16 (h3 reuses) | h2 64xH2S bf16 (kern 64xKS f32 aliases)
  __shared__ __attribute__((aligned(16))) char smem[256 + 64*H1S*2 + 64*H2S*2];
  int*   s_idx  = (int*)smem;
  short* s_h1   = (short*)(smem + 256);
  short* s_h2   = (short*)(smem + 256 + 64*H1S*2);
  float* s_kern = (float*)(smem + 256 + 64*H1S*2);   // alias of s_h2

  const int tid  = threadIdx.x;
  const int e0   = blockIdx.x * 64;
  if (tid < 64) s_idx[tid] = nidx[e0 + tid];
  const int wave = tid >> 6, lane = tid & 63;
  const int quad = lane >> 4, l15 = lane & 15;
  __syncthreads();

  // ---------- layer 0: per-wave M=16 (exactly-once gather), N=128, GELU ----------
  // A-frag row (local) m = l15 -> global edge er; prefetch ALL 12 K-chunks up-front.
  {
    const int er = e0 + wave * 16 + l15;
    const short* yrow = yemb + (size_t)s_idx[wave * 16 + l15] * EMB_DIM + quad * 8;
    const short* xrow = xemb + (size_t)(er >> 3) * EMB_DIM + quad * 8;

    bf16x8 a[12];
    #pragma unroll
    for (int ch = 0; ch < 6; ++ch)  a[ch]     = *(const bf16x8*)(yrow + ch * 32);
    #pragma unroll
    for (int ch = 0; ch < 6; ++ch)  a[ch + 6] = *(const bf16x8*)(xrow + ch * 32);

    f32x4 acc0[8];
    #pragma unroll
    for (int nt = 0; nt < 8; ++nt) acc0[nt] = (f32x4){0.f, 0.f, 0.f, 0.f};

    #pragma unroll
    for (int ch = 0; ch < 12; ++ch) {
      #pragma unroll
      for (int nt = 0; nt < 8; ++nt) {
        bf16x8 b = *(const bf16x8*)&w0t[(size_t)(nt * 16 + l15) * 384 + ch * 32 + quad * 8];
        acc0[nt] = __builtin_amdgcn_mfma_f32_16x16x32_bf16(a[ch], b, acc0[nt], 0, 0, 0);
      }
    }
    #pragma unroll
    for (int nt = 0; nt < 8; ++nt) {
      int col = nt * 16 + l15;
      float bias = b0[col];
      #pragma unroll
      for (int rg = 0; rg < 4; ++rg) {
        int row = wave * 16 + quad * 4 + rg;       // global row in 64-edge tile
        s_h1[row * H1S + col] = f2bf(geluf(acc0[nt][rg] + bias));
      }
    }
  }
  __syncthreads();

  // ---------- layer 1: 128 -> 256, GELU (N-split: wave owns 64 cols) ----------
  {
    f32x4 acc1[4][4];
    #pragma unroll
    for (int mt = 0; mt < 4; ++mt)
      #pragma unroll
      for (int nt = 0; nt < 4; ++nt) acc1[mt][nt] = (f32x4){0.f, 0.f, 0.f, 0.f};
    #pragma unroll
    for (int ch = 0; ch < 4; ++ch) {
      bf16x8 a[4], b[4];
      #pragma unroll
      for (int mt = 0; mt < 4; ++mt)
        a[mt] = *(const bf16x8*)&s_h1[(mt * 16 + l15) * H1S + ch * 32 + quad * 8];
      #pragma unroll
      for (int nt = 0; nt < 4; ++nt)
        b[nt] = *(const bf16x8*)&w1t[(size_t)(wave * 64 + nt * 16 + l15) * 128 + ch * 32 + quad * 8];
      #pragma unroll
      for (int mt = 0; mt < 4; ++mt)
        #pragma unroll
        for (int nt = 0; nt < 4; ++nt)
          acc1[mt][nt] = __builtin_amdgcn_mfma_f32_16x16x32_bf16(a[mt], b[nt], acc1[mt][nt], 0, 0, 0);
    }
    #pragma unroll
    for (int nt = 0; nt < 4; ++nt) {
      int col = wave * 64 + nt * 16 + l15;
      float bias = b1[col];
      #pragma unroll
      for (int mt = 0; mt < 4; ++mt)
        #pragma unroll
        for (int rg = 0; rg < 4; ++rg) {
          int row = mt * 16 + quad * 4 + rg;
          s_h2[row * H2S + col] = f2bf(geluf(acc1[mt][nt][rg] + bias));
        }
    }
  }
  __syncthreads();   // h2 visible; also: all h1 reads done -> h3 may overwrite h1 region

  // ---------- layer 2: 256 -> 128, GELU (N-split: wave owns 32 cols) ----------
  {
    f32x4 acc2[4][2];
    #pragma unroll
    for (int mt = 0; mt < 4; ++mt)
      #pragma unroll
      for (int nt = 0; nt < 2; ++nt) acc2[mt][nt] = (f32x4){0.f, 0.f, 0.f, 0.f};
    #pragma unroll
    for (int ch = 0; ch < 8; ++ch) {
      bf16x8 a[4], b[2];
      #pragma unroll
      for (int mt = 0; mt < 4; ++mt)
        a[mt] = *(const bf16x8*)&s_h2[(mt * 16 + l15) * H2S + ch * 32 + quad * 8];
      #pragma unroll
      for (int nt = 0; nt < 2; ++nt)
        b[nt] = *(const bf16x8*)&w2t[(size_t)(wave * 32 + nt * 16 + l15) * 256 + ch * 32 + quad * 8];
      #pragma unroll
      for (int mt = 0; mt < 4; ++mt)
        #pragma unroll
        for (int nt = 0; nt < 2; ++nt)
          acc2[mt][nt] = __builtin_amdgcn_mfma_f32_16x16x32_bf16(a[mt], b[nt], acc2[mt][nt], 0, 0, 0);
    }
    // h3 -> s_h1 region (safe: all h1 reads fenced by the post-h2 barrier)
    #pragma unroll
    for (int nt = 0; nt < 2; ++nt) {
      int col = wave * 32 + nt * 16 + l15;
      float bias = b2[col];
      #pragma unroll
      for (int mt = 0; mt < 4; ++mt)
        #pragma unroll
        for (int rg = 0; rg < 4; ++rg) {
          int row = mt * 16 + quad * 4 + rg;
          s_h1[row * H1S + col] = f2bf(geluf(acc2[mt][nt][rg] + bias));
        }
    }
  }
  __syncthreads();   // h3 visible; all h2 reads done -> kern may alias h2 region

  // ---------- layer 3: 128 -> 32 linear (M-split: wave owns 16 rows) -> s_kern ----------
  {
    f32x4 acc3[2];
    acc3[0] = (f32x4){0.f, 0.f, 0.f, 0.f};
    acc3[1] = (f32x4){0.f, 0.f, 0.f, 0.f};
    #pragma unroll
    for (int ch = 0; ch < 4; ++ch) {
      bf16x8 a3 = *(const bf16x8*)&s_h1[(wave * 16 + l15) * H1S + ch * 32 + quad * 8];
      #pragma unroll
      for (int nt = 0; nt < 2; ++nt) {
        bf16x8 b3f = *(const bf16x8*)&w3t[(size_t)(nt * 16 + l15) * 128 + ch * 32 + quad * 8];
        acc3[nt] = __builtin_amdgcn_mfma_f32_16x16x32_bf16(a3, b3f, acc3[nt], 0, 0, 0);
      }
    }
    #pragma unroll
    for (int nt = 0; nt < 2; ++nt) {
      int col = nt * 16 + l15;
      float bias = b3[col];
      #pragma unroll
      for (int rg = 0; rg < 4; ++rg) {
        int row = wave * 16 + quad * 4 + rg;
        s_kern[row * KS + col] = acc3[nt][rg] + bias;
      }
    }
  }
  __syncthreads();

  // ---------- fused reduce: out[t][x][c] = sum_j kern[x*8+j][c] * f_y[t][idx][c] ----------
  {
    const int xloc = tid >> 5;     // 0..7 local x-point
    const int c    = tid & 31;
    float acc[TDIM] = {0.f, 0.f, 0.f, 0.f};
    const int ebase = xloc * 8;
    #pragma unroll
    for (int j = 0; j < KNBR; ++j) {
      float kv = s_kern[(ebase + j) * KS + c];
      int idx = s_idx[ebase + j];
      const float* fp = f_y + (size_t)idx * CDIM + c;
      #pragma unroll
      for (int t = 0; t < TDIM; ++t)
        acc[t] += kv * fp[(size_t)t * N_Y * CDIM];
    }
    const int xg = blockIdx.x * 8 + xloc;
    #pragma unroll
    for (int t = 0; t < TDIM; ++t)
      out[((size_t)t * N_X + xg) * CDIM + c] = acc[t];
  }
}

extern "C" void kernel_launch(void* const* d_in, const int* in_sizes, int n_in,
                              void* d_out, int out_size, void* d_ws, size_t ws_size,
                              hipStream_t stream)
{
  const float* y   = (const float*)d_in[0];
  const float* x   = (const float*)d_in[1];
  const float* f_y = (const float*)d_in[2];
  const int*  nidx = (const int*)d_in[3];
  const float* W0 = (const float*)d_in[4];  const float* b0 = (const float*)d_in[5];
  const float* W1 = (const float*)d_in[6];  const float* b1 = (const float*)d_in[7];
  const float* W2 = (const float*)d_in[8];  const float* b2 = (const float*)d_in[9];
  const float* W3 = (const float*)d_in[10]; const float* b3 = (const float*)d_in[11];

  char* ws = (char*)d_ws;
  short* yemb = (short*)(ws + 0);          // 50000*192*2 = 19,200,000
  short* xemb = (short*)(ws + 19200000);   // 32768*192*2 = 12,582,912
  short* w0t  = (short*)(ws + 31782912);   // 128*384*2  =     98,304
  short* w1t  = (short*)(ws + 31881216);   // 256*128*2  =     65,536
  short* w2t  = (short*)(ws + 31946752);   // 128*256*2  =     65,536
  short* w3t  = (short*)(ws + 32012288);   //  32*128*2  =      8,192

  hipLaunchKernelGGL(embed_all, dim3(((N_Y + N_X) * 96 + 255) / 256), dim3(256), 0, stream,
                     y, x, yemb);
  hipLaunchKernelGGL(transpose_all, dim3((118784 + 255) / 256), dim3(256), 0, stream,
                     W0, W1, W2, W3, w0t, w1t, w2t, w3t);
  hipLaunchKernelGGL(fused_mlp, dim3(ECNT / 64), dim3(256), 0, stream,
                     yemb, xemb, nidx, f_y, w0t, b0, w1t, b1, w2t, b2, w3t, b3,
                     (float*)d_out);
}

// Round 4
// 279.197 us; speedup vs baseline: 1.3376x; 1.3376x over previous
//
#include <hip/hip_runtime.h>
#include <stdint.h>

#define EMB_DIM 192      // 3 coords * 32 freqs * 2 (sin,cos)
#define KIN 384
#define CDIM 32
#define TDIM 4
#define N_Y 50000
#define N_X 32768
#define KNBR 8
#define ECNT (N_X*KNBR)  // 262144

// LDS row strides (shorts). A: 200 (400B, 16B-aligned, words/4=25 odd -> spread).
// h1: 134, h2: 262 (odd-word, proven 0.26M confl in R3).
#define AS  200
#define H1S 134
#define H2S 262
#define KS  33

typedef __attribute__((ext_vector_type(8))) short bf16x8;
typedef __attribute__((ext_vector_type(4))) float f32x4;

static __device__ __forceinline__ short f2bf(float f){
  unsigned u = __float_as_uint(f);
  return (short)((u + 0x7FFFu) >> 16);
}
static __device__ __forceinline__ float geluf(float x){
  float x2 = x * x;
  float u  = __builtin_fmaf(0.044715f, x2, 1.0f);
  float p  = x * -1.5957691216057308f;      // -2*0.7978845608
  float e  = __expf(p * u);                 // exp(-2t)
  return x * __builtin_amdgcn_rcpf(1.0f + e);
}

// ---- embeddings for y (rows 0..N_Y-1) and x (rows N_Y..): one launch ----
__global__ __launch_bounds__(256) void embed_all(const float* __restrict__ ypts,
                                                 const float* __restrict__ xpts,
                                                 short* __restrict__ emb){
  int id = blockIdx.x * 256 + threadIdx.x;
  int total = (N_Y + N_X) * 96;
  if (id >= total) return;
  int row = id / 96;
  int q = id - row * 96;
  int d = q >> 5, i = q & 31;
  float p = (row < N_Y) ? ypts[row * 3 + d] : xpts[(row - N_Y) * 3 + d];
  float f = __expf(-9.210340371976184f * (float)i * (1.0f / 32.0f));
  float s, c;
  __sincosf(p * f, &s, &c);
  unsigned u0 = __float_as_uint(s), u1 = __float_as_uint(c);
  unsigned pack = ((u0 + 0x7FFFu) >> 16) | (((u1 + 0x7FFFu) >> 16) << 16);
  *(unsigned*)&emb[(size_t)row * EMB_DIM + d * 64 + 2 * i] = pack;
}

// ---- all four W (K,N) fp32 -> W^T (N,K) bf16 in one launch ----
__global__ __launch_bounds__(256) void transpose_all(
    const float* __restrict__ W0, const float* __restrict__ W1,
    const float* __restrict__ W2, const float* __restrict__ W3,
    short* __restrict__ w0t, short* __restrict__ w1t,
    short* __restrict__ w2t, short* __restrict__ w3t){
  int id = blockIdx.x * 256 + threadIdx.x;
  const float* src; short* dst; int K, N, loc;
  if      (id < 49152)  { src = W0; dst = w0t; K = 384; N = 128; loc = id; }
  else if (id < 81920)  { src = W1; dst = w1t; K = 128; N = 256; loc = id - 49152; }
  else if (id < 114688) { src = W2; dst = w2t; K = 256; N = 128; loc = id - 81920; }
  else if (id < 118784) { src = W3; dst = w3t; K = 128; N = 32;  loc = id - 114688; }
  else return;
  int n = loc / K, k = loc - n * K;
  dst[n * K + k] = f2bf(src[k * N + n]);
}

// ---- fused: gather-MLP (4 layers, MFMA) + K=8 segment reduce, per 64-edge block ----
// Region plan (aliasing fenced by barriers):
//   region1 [0, 33536): y-A tile (64xAS=25600) -> h2 (64xH2S*2=33536) -> kern (64xKS*4=8448)
//   region2 [33536, 50688): h1 (64xH1S*2=17152), later h3 (same layout)
__global__ __launch_bounds__(256, 3) void fused_mlp(
    const short* __restrict__ yemb, const short* __restrict__ xemb,
    const int* __restrict__ nidx, const float* __restrict__ f_y,
    const short* __restrict__ w0t, const float* __restrict__ b0,
    const short* __restrict__ w1t, const float* __restrict__ b1,
    const short* __restrict__ w2t, const float* __restrict__ b2,
    const short* __restrict__ w3t, const float* __restrict__ b3,
    float* __restrict__ out)
{
  __shared__ __attribute__((aligned(16))) char smem[50688];
  short* s_a    = (short*)smem;                  // 64 x AS
  short* s_h2   = (short*)smem;                  // 64 x H2S (after A dead)
  float* s_kern = (float*)smem;                  // 64 x KS  (after h2 dead)
  short* s_h1   = (short*)(smem + 33536);        // 64 x H1S (h3 reuses)

  const int tid  = threadIdx.x;
  const int e0   = blockIdx.x * 64;
  const int wave = tid >> 6, lane = tid & 63;
  const int quad = lane >> 4, l15 = lane & 15;

  // ---- stage y-embeddings for all 64 edges: 6 x 16B per thread, ONE barrier ----
  {
    const int r = tid >> 2, q = tid & 3;                  // row 0..63, quarter
    const int idx_r = nidx[e0 + r];
    const short* yrow = yemb + (size_t)idx_r * EMB_DIM + q * 48;   // 48 shorts = 96 B
    uint4 v[6];
    #pragma unroll
    for (int i = 0; i < 6; ++i) v[i] = *(const uint4*)(yrow + i * 8);
    #pragma unroll
    for (int i = 0; i < 6; ++i)
      *(uint4*)&s_a[r * AS + q * 48 + i * 8] = v[i];
  }
  __syncthreads();

  // ---------- layer 0: 384 -> 128, GELU. A: y from LDS (ch<6), x direct (ch>=6) ----------
  {
    const short* xrow[4];
    #pragma unroll
    for (int mt = 0; mt < 4; ++mt)
      xrow[mt] = xemb + (size_t)((e0 + mt * 16 + l15) >> 3) * EMB_DIM + quad * 8;

    f32x4 acc0[4][2];
    #pragma unroll
    for (int mt = 0; mt < 4; ++mt)
      #pragma unroll
      for (int nt = 0; nt < 2; ++nt) acc0[mt][nt] = (f32x4){0.f, 0.f, 0.f, 0.f};

    #pragma unroll
    for (int ch = 0; ch < 12; ++ch) {
      bf16x8 a[4], b[2];
      #pragma unroll
      for (int mt = 0; mt < 4; ++mt) {
        if (ch < 6) a[mt] = *(const bf16x8*)&s_a[(mt * 16 + l15) * AS + ch * 32 + quad * 8];
        else        a[mt] = *(const bf16x8*)(xrow[mt] + (ch - 6) * 32);
      }
      #pragma unroll
      for (int nt = 0; nt < 2; ++nt)
        b[nt] = *(const bf16x8*)&w0t[(size_t)(wave * 32 + nt * 16 + l15) * 384 + ch * 32 + quad * 8];
      #pragma unroll
      for (int mt = 0; mt < 4; ++mt)
        #pragma unroll
        for (int nt = 0; nt < 2; ++nt)
          acc0[mt][nt] = __builtin_amdgcn_mfma_f32_16x16x32_bf16(a[mt], b[nt], acc0[mt][nt], 0, 0, 0);
    }
    #pragma unroll
    for (int nt = 0; nt < 2; ++nt) {
      int col = wave * 32 + nt * 16 + l15;
      float bias = b0[col];
      #pragma unroll
      for (int mt = 0; mt < 4; ++mt)
        #pragma unroll
        for (int rg = 0; rg < 4; ++rg) {
          int row = mt * 16 + quad * 4 + rg;
          s_h1[row * H1S + col] = f2bf(geluf(acc0[mt][nt][rg] + bias));
        }
    }
  }
  __syncthreads();   // h1 visible; A reads done -> h2 may overwrite region1

  // ---------- layer 1: 128 -> 256, GELU (N-split: wave owns 64 cols) ----------
  {
    f32x4 acc1[4][4];
    #pragma unroll
    for (int mt = 0; mt < 4; ++mt)
      #pragma unroll
      for (int nt = 0; nt < 4; ++nt) acc1[mt][nt] = (f32x4){0.f, 0.f, 0.f, 0.f};
    #pragma unroll
    for (int ch = 0; ch < 4; ++ch) {
      bf16x8 a[4], b[4];
      #pragma unroll
      for (int mt = 0; mt < 4; ++mt)
        a[mt] = *(const bf16x8*)&s_h1[(mt * 16 + l15) * H1S + ch * 32 + quad * 8];
      #pragma unroll
      for (int nt = 0; nt < 4; ++nt)
        b[nt] = *(const bf16x8*)&w1t[(size_t)(wave * 64 + nt * 16 + l15) * 128 + ch * 32 + quad * 8];
      #pragma unroll
      for (int mt = 0; mt < 4; ++mt)
        #pragma unroll
        for (int nt = 0; nt < 4; ++nt)
          acc1[mt][nt] = __builtin_amdgcn_mfma_f32_16x16x32_bf16(a[mt], b[nt], acc1[mt][nt], 0, 0, 0);
    }
    #pragma unroll
    for (int nt = 0; nt < 4; ++nt) {
      int col = wave * 64 + nt * 16 + l15;
      float bias = b1[col];
      #pragma unroll
      for (int mt = 0; mt < 4; ++mt)
        #pragma unroll
        for (int rg = 0; rg < 4; ++rg) {
          int row = mt * 16 + quad * 4 + rg;
          s_h2[row * H2S + col] = f2bf(geluf(acc1[mt][nt][rg] + bias));
        }
    }
  }
  __syncthreads();   // h2 visible; h1 reads done -> h3 may overwrite region2

  // ---------- layer 2: 256 -> 128, GELU (N-split: wave owns 32 cols) ----------
  {
    f32x4 acc2[4][2];
    #pragma unroll
    for (int mt = 0; mt < 4; ++mt)
      #pragma unroll
      for (int nt = 0; nt < 2; ++nt) acc2[mt][nt] = (f32x4){0.f, 0.f, 0.f, 0.f};
    #pragma unroll
    for (int ch = 0; ch < 8; ++ch) {
      bf16x8 a[4], b[2];
      #pragma unroll
      for (int mt = 0; mt < 4; ++mt)
        a[mt] = *(const bf16x8*)&s_h2[(mt * 16 + l15) * H2S + ch * 32 + quad * 8];
      #pragma unroll
      for (int nt = 0; nt < 2; ++nt)
        b[nt] = *(const bf16x8*)&w2t[(size_t)(wave * 32 + nt * 16 + l15) * 256 + ch * 32 + quad * 8];
      #pragma unroll
      for (int mt = 0; mt < 4; ++mt)
        #pragma unroll
        for (int nt = 0; nt < 2; ++nt)
          acc2[mt][nt] = __builtin_amdgcn_mfma_f32_16x16x32_bf16(a[mt], b[nt], acc2[mt][nt], 0, 0, 0);
    }
    #pragma unroll
    for (int nt = 0; nt < 2; ++nt) {
      int col = wave * 32 + nt * 16 + l15;
      float bias = b2[col];
      #pragma unroll
      for (int mt = 0; mt < 4; ++mt)
        #pragma unroll
        for (int rg = 0; rg < 4; ++rg) {
          int row = mt * 16 + quad * 4 + rg;
          s_h1[row * H1S + col] = f2bf(geluf(acc2[mt][nt][rg] + bias));   // h3
        }
    }
  }
  __syncthreads();   // h3 visible; h2 reads done -> kern may overwrite region1

  // ---------- layer 3: 128 -> 32 linear (M-split: wave owns 16 rows) -> s_kern ----------
  {
    f32x4 acc3[2];
    acc3[0] = (f32x4){0.f, 0.f, 0.f, 0.f};
    acc3[1] = (f32x4){0.f, 0.f, 0.f, 0.f};
    #pragma unroll
    for (int ch = 0; ch < 4; ++ch) {
      bf16x8 a3 = *(const bf16x8*)&s_h1[(wave * 16 + l15) * H1S + ch * 32 + quad * 8];
      #pragma unroll
      for (int nt = 0; nt < 2; ++nt) {
        bf16x8 b3f = *(const bf16x8*)&w3t[(size_t)(nt * 16 + l15) * 128 + ch * 32 + quad * 8];
        acc3[nt] = __builtin_amdgcn_mfma_f32_16x16x32_bf16(a3, b3f, acc3[nt], 0, 0, 0);
      }
    }
    #pragma unroll
    for (int nt = 0; nt < 2; ++nt) {
      int col = nt * 16 + l15;
      float bias = b3[col];
      #pragma unroll
      for (int rg = 0; rg < 4; ++rg) {
        int row = wave * 16 + quad * 4 + rg;
        s_kern[row * KS + col] = acc3[nt][rg] + bias;
      }
    }
  }
  __syncthreads();

  // ---------- fused reduce: out[t][x][c] = sum_j kern[x*8+j][c] * f_y[t][idx][c] ----------
  {
    const int xloc = tid >> 5;     // 0..7 local x-point
    const int c    = tid & 31;
    float acc[TDIM] = {0.f, 0.f, 0.f, 0.f};
    const int ebase = xloc * 8;
    #pragma unroll
    for (int j = 0; j < KNBR; ++j) {
      float kv = s_kern[(ebase + j) * KS + c];
      int idx = nidx[e0 + ebase + j];            // L1-warm reload
      const float* fp = f_y + (size_t)idx * CDIM + c;
      #pragma unroll
      for (int t = 0; t < TDIM; ++t)
        acc[t] += kv * fp[(size_t)t * N_Y * CDIM];
    }
    const int xg = blockIdx.x * 8 + xloc;
    #pragma unroll
    for (int t = 0; t < TDIM; ++t)
      out[((size_t)t * N_X + xg) * CDIM + c] = acc[t];
  }
}

extern "C" void kernel_launch(void* const* d_in, const int* in_sizes, int n_in,
                              void* d_out, int out_size, void* d_ws, size_t ws_size,
                              hipStream_t stream)
{
  const float* y   = (const float*)d_in[0];
  const float* x   = (const float*)d_in[1];
  const float* f_y = (const float*)d_in[2];
  const int*  nidx = (const int*)d_in[3];
  const float* W0 = (const float*)d_in[4];  const float* b0 = (const float*)d_in[5];
  const float* W1 = (const float*)d_in[6];  const float* b1 = (const float*)d_in[7];
  const float* W2 = (const float*)d_in[8];  const float* b2 = (const float*)d_in[9];
  const float* W3 = (const float*)d_in[10]; const float* b3 = (const float*)d_in[11];

  char* ws = (char*)d_ws;
  short* yemb = (short*)(ws + 0);          // 50000*192*2 = 19,200,000
  short* xemb = (short*)(ws + 19200000);   // 32768*192*2 = 12,582,912
  short* w0t  = (short*)(ws + 31782912);   // 128*384*2
  short* w1t  = (short*)(ws + 31881216);   // 256*128*2
  short* w2t  = (short*)(ws + 31946752);   // 128*256*2
  short* w3t  = (short*)(ws + 32012288);   //  32*128*2

  hipLaunchKernelGGL(embed_all, dim3(((N_Y + N_X) * 96 + 255) / 256), dim3(256), 0, stream,
                     y, x, yemb);
  hipLaunchKernelGGL(transpose_all, dim3((118784 + 255) / 256), dim3(256), 0, stream,
                     W0, W1, W2, W3, w0t, w1t, w2t, w3t);
  hipLaunchKernelGGL(fused_mlp, dim3(ECNT / 64), dim3(256), 0, stream,
                     yemb, xemb, nidx, f_y, w0t, b0, w1t, b1, w2t, b2, w3t, b3,
                     (float*)d_out);
}

// Round 5
// 241.940 us; speedup vs baseline: 1.5436x; 1.1540x over previous
//
#include <hip/hip_runtime.h>
#include <stdint.h>

#define EMB_DIM 192
#define CDIM 32
#define TDIM 4
#define N_Y 50000
#define N_X 32768
#define KNBR 8
#define ECNT (N_X*KNBR)  // 262144

// LDS row strides (shorts), odd-word -> low conflicts (proven R3/R4)
#define H1S 134
#define H2S 262
#define KS  33
#define ES  200   // precompute emb stage stride (400B rows, 16B-aligned)

typedef __attribute__((ext_vector_type(8))) short bf16x8;
typedef __attribute__((ext_vector_type(4))) float f32x4;

static __device__ __forceinline__ short f2bf(float f){
  unsigned u = __float_as_uint(f);
  return (short)((u + 0x7FFFu) >> 16);
}
static __device__ __forceinline__ float geluf(float x){
  float x2 = x * x;
  float u  = __builtin_fmaf(0.044715f, x2, 1.0f);
  float p  = x * -1.5957691216057308f;      // -2*0.7978845608
  float e  = __expf(p * u);                 // exp(-2t)
  return x * __builtin_amdgcn_rcpf(1.0f + e);
}

// ---- weights: W(K,N) fp32 -> W^T(N,K) bf16; W0 split into y-half / x-half of K ----
__global__ __launch_bounds__(256) void transpose_all(
    const float* __restrict__ W0, const float* __restrict__ W1,
    const float* __restrict__ W2, const float* __restrict__ W3,
    short* __restrict__ w0yt, short* __restrict__ w0xt,
    short* __restrict__ w1t, short* __restrict__ w2t, short* __restrict__ w3t){
  int id = blockIdx.x * 256 + threadIdx.x;
  if (id < 24576) {              // w0yt[n*192+k] = W0[k][n], k<192
    int n = id / 192, k = id - n * 192;
    w0yt[id] = f2bf(W0[k * 128 + n]);
  } else if (id < 49152) {       // w0xt[n*192+k] = W0[k+192][n]
    int loc = id - 24576; int n = loc / 192, k = loc - n * 192;
    w0xt[loc] = f2bf(W0[(k + 192) * 128 + n]);
  } else if (id < 81920) {       // w1t[n*128+k] = W1[k][n]  (128x256)
    int loc = id - 49152; int n = loc / 128, k = loc - n * 128;
    w1t[loc] = f2bf(W1[k * 256 + n]);
  } else if (id < 114688) {      // w2t[n*256+k] = W2[k][n]  (256x128)
    int loc = id - 81920; int n = loc / 256, k = loc - n * 256;
    w2t[loc] = f2bf(W2[k * 128 + n]);
  } else if (id < 118784) {      // w3t[n*128+k] = W3[k][n]  (128x32)
    int loc = id - 114688; int n = loc / 128, k = loc - n * 128;
    w3t[loc] = f2bf(W3[k * 32 + n]);
  }
}

// ---- precompute: embed row on the fly -> GEMM vs W0-half ----
// blocks [0,782): y rows -> c_y bf16 (no bias); blocks [782,1294): x rows -> c_x fp32 (+b0)
__global__ __launch_bounds__(256, 2) void precompute_c(
    const float* __restrict__ ypts, const float* __restrict__ xpts,
    const short* __restrict__ w0yt, const short* __restrict__ w0xt,
    const float* __restrict__ b0,
    short* __restrict__ c_y, float* __restrict__ c_x)
{
  __shared__ __attribute__((aligned(16))) short s_e[64 * ES];
  const int tid = threadIdx.x;
  const bool isY = blockIdx.x < 782;
  const int row0 = isY ? blockIdx.x * 64 : (blockIdx.x - 782) * 64;
  const int wave = tid >> 6, lane = tid & 63;
  const int quad = lane >> 4, l15 = lane & 15;

  // embed phase: thread (r,q) computes 24 (d,i) pairs
  {
    const int r = tid >> 2, q = tid & 3;
    const int grow = row0 + r;
    const bool valid = isY ? (grow < N_Y) : true;
    const float* src = isY ? (ypts + (size_t)grow * 3) : (xpts + (size_t)grow * 3);
    float c[3] = {0.f, 0.f, 0.f};
    if (valid) { c[0] = src[0]; c[1] = src[1]; c[2] = src[2]; }
    #pragma unroll
    for (int j = 0; j < 24; ++j) {
      int p = q * 24 + j;
      int d = p >> 5, i = p & 31;
      float f = __expf(-0.28782313662425575f * (float)i);   // (1e-4)^(i/32)
      float s, co;
      __sincosf(c[d] * f, &s, &co);
      unsigned u0 = __float_as_uint(s), u1 = __float_as_uint(co);
      unsigned pk = ((u0 + 0x7FFFu) >> 16) | (((u1 + 0x7FFFu) >> 16) << 16);
      *(unsigned*)&s_e[r * ES + d * 64 + 2 * i] = pk;
    }
  }
  __syncthreads();

  // GEMM: 64 x 192 @ 192 x 128, wave owns 32 cols
  const short* w0t = isY ? w0yt : w0xt;
  f32x4 acc[4][2];
  #pragma unroll
  for (int mt = 0; mt < 4; ++mt)
    #pragma unroll
    for (int nt = 0; nt < 2; ++nt) acc[mt][nt] = (f32x4){0.f, 0.f, 0.f, 0.f};
  #pragma unroll
  for (int ch = 0; ch < 6; ++ch) {
    bf16x8 a[4], b[2];
    #pragma unroll
    for (int mt = 0; mt < 4; ++mt)
      a[mt] = *(const bf16x8*)&s_e[(mt * 16 + l15) * ES + ch * 32 + quad * 8];
    #pragma unroll
    for (int nt = 0; nt < 2; ++nt)
      b[nt] = *(const bf16x8*)&w0t[(size_t)(wave * 32 + nt * 16 + l15) * 192 + ch * 32 + quad * 8];
    #pragma unroll
    for (int mt = 0; mt < 4; ++mt)
      #pragma unroll
      for (int nt = 0; nt < 2; ++nt)
        acc[mt][nt] = __builtin_amdgcn_mfma_f32_16x16x32_bf16(a[mt], b[nt], acc[mt][nt], 0, 0, 0);
  }
  #pragma unroll
  for (int nt = 0; nt < 2; ++nt) {
    int col = wave * 32 + nt * 16 + l15;
    float bias = isY ? 0.f : b0[col];
    #pragma unroll
    for (int mt = 0; mt < 4; ++mt)
      #pragma unroll
      for (int rg = 0; rg < 4; ++rg) {
        int grow = row0 + mt * 16 + quad * 4 + rg;
        if (isY) { if (grow < N_Y) c_y[(size_t)grow * 128 + col] = f2bf(acc[mt][nt][rg]); }
        else     { c_x[(size_t)grow * 128 + col] = acc[mt][nt][rg] + bias; }
      }
  }
}

// ---- edge kernel: gather c_y/c_x -> add+GELU -> L1 -> L2 -> L3 -> K=8 reduce ----
// region1 [0,33536): h2 (64xH2S bf16), later kern (64xKS f32)
// region2 [33536,50688): h1 (64xH1S bf16), later h3
__global__ __launch_bounds__(256, 3) void fused_edge(
    const short* __restrict__ c_y, const float* __restrict__ c_x,
    const int* __restrict__ nidx, const float* __restrict__ f_y,
    const short* __restrict__ w1t, const float* __restrict__ b1,
    const short* __restrict__ w2t, const float* __restrict__ b2,
    const short* __restrict__ w3t, const float* __restrict__ b3,
    float* __restrict__ out)
{
  __shared__ __attribute__((aligned(16))) char smem[50688];
  short* s_h2   = (short*)smem;
  float* s_kern = (float*)smem;
  short* s_h1   = (short*)(smem + 33536);

  const int tid  = threadIdx.x;
  const int e0   = blockIdx.x * 64;
  const int wave = tid >> 6, lane = tid & 63;
  const int quad = lane >> 4, l15 = lane & 15;

  // ---- phase 0: h1 = gelu(c_y[idx] + c_x[e>>3]); thread (r,q) does 32 cols ----
  {
    const int r = tid >> 2, q = tid & 3;
    const int idx = nidx[e0 + r];
    const uint4*  cyp = (const uint4*)(c_y + (size_t)idx * 128 + q * 32);
    const float4* cxp = (const float4*)(c_x + (size_t)((e0 + r) >> 3) * 128 + q * 32);
    uint4  cyv[4];
    float4 cxv[8];
    #pragma unroll
    for (int i = 0; i < 4; ++i) cyv[i] = cyp[i];
    #pragma unroll
    for (int i = 0; i < 8; ++i) cxv[i] = cxp[i];
    const float* cxa = (const float*)cxv;
    const unsigned* cya = (const unsigned*)cyv;
    unsigned* dst = (unsigned*)&s_h1[r * H1S + q * 32];
    #pragma unroll
    for (int jj = 0; jj < 16; ++jj) {
      unsigned u = cya[jj];
      float lo = __uint_as_float(u << 16)         + cxa[2 * jj];
      float hi = __uint_as_float(u & 0xffff0000u) + cxa[2 * jj + 1];
      unsigned pk = (unsigned)(unsigned short)f2bf(geluf(lo)) |
                    ((unsigned)(unsigned short)f2bf(geluf(hi)) << 16);
      dst[jj] = pk;
    }
  }
  __syncthreads();

  // ---------- layer 1: 128 -> 256, GELU (wave owns 64 cols) ----------
  {
    f32x4 acc1[4][4];
    #pragma unroll
    for (int mt = 0; mt < 4; ++mt)
      #pragma unroll
      for (int nt = 0; nt < 4; ++nt) acc1[mt][nt] = (f32x4){0.f, 0.f, 0.f, 0.f};
    #pragma unroll
    for (int ch = 0; ch < 4; ++ch) {
      bf16x8 a[4], b[4];
      #pragma unroll
      for (int mt = 0; mt < 4; ++mt)
        a[mt] = *(const bf16x8*)&s_h1[(mt * 16 + l15) * H1S + ch * 32 + quad * 8];
      #pragma unroll
      for (int nt = 0; nt < 4; ++nt)
        b[nt] = *(const bf16x8*)&w1t[(size_t)(wave * 64 + nt * 16 + l15) * 128 + ch * 32 + quad * 8];
      #pragma unroll
      for (int mt = 0; mt < 4; ++mt)
        #pragma unroll
        for (int nt = 0; nt < 4; ++nt)
          acc1[mt][nt] = __builtin_amdgcn_mfma_f32_16x16x32_bf16(a[mt], b[nt], acc1[mt][nt], 0, 0, 0);
    }
    #pragma unroll
    for (int nt = 0; nt < 4; ++nt) {
      int col = wave * 64 + nt * 16 + l15;
      float bias = b1[col];
      #pragma unroll
      for (int mt = 0; mt < 4; ++mt)
        #pragma unroll
        for (int rg = 0; rg < 4; ++rg) {
          int row = mt * 16 + quad * 4 + rg;
          s_h2[row * H2S + col] = f2bf(geluf(acc1[mt][nt][rg] + bias));
        }
    }
  }
  __syncthreads();   // h2 visible; h1 reads done -> h3 may overwrite region2

  // ---------- layer 2: 256 -> 128, GELU (wave owns 32 cols) ----------
  {
    f32x4 acc2[4][2];
    #pragma unroll
    for (int mt = 0; mt < 4; ++mt)
      #pragma unroll
      for (int nt = 0; nt < 2; ++nt) acc2[mt][nt] = (f32x4){0.f, 0.f, 0.f, 0.f};
    #pragma unroll
    for (int ch = 0; ch < 8; ++ch) {
      bf16x8 a[4], b[2];
      #pragma unroll
      for (int mt = 0; mt < 4; ++mt)
        a[mt] = *(const bf16x8*)&s_h2[(mt * 16 + l15) * H2S + ch * 32 + quad * 8];
      #pragma unroll
      for (int nt = 0; nt < 2; ++nt)
        b[nt] = *(const bf16x8*)&w2t[(size_t)(wave * 32 + nt * 16 + l15) * 256 + ch * 32 + quad * 8];
      #pragma unroll
      for (int mt = 0; mt < 4; ++mt)
        #pragma unroll
        for (int nt = 0; nt < 2; ++nt)
          acc2[mt][nt] = __builtin_amdgcn_mfma_f32_16x16x32_bf16(a[mt], b[nt], acc2[mt][nt], 0, 0, 0);
    }
    #pragma unroll
    for (int nt = 0; nt < 2; ++nt) {
      int col = wave * 32 + nt * 16 + l15;
      float bias = b2[col];
      #pragma unroll
      for (int mt = 0; mt < 4; ++mt)
        #pragma unroll
        for (int rg = 0; rg < 4; ++rg) {
          int row = mt * 16 + quad * 4 + rg;
          s_h1[row * H1S + col] = f2bf(geluf(acc2[mt][nt][rg] + bias));   // h3
        }
    }
  }
  __syncthreads();   // h3 visible; h2 reads done -> kern may overwrite region1

  // ---------- layer 3: 128 -> 32 linear (wave owns 16 rows) -> s_kern ----------
  {
    f32x4 acc3[2];
    acc3[0] = (f32x4){0.f, 0.f, 0.f, 0.f};
    acc3[1] = (f32x4){0.f, 0.f, 0.f, 0.f};
    #pragma unroll
    for (int ch = 0; ch < 4; ++ch) {
      bf16x8 a3 = *(const bf16x8*)&s_h1[(wave * 16 + l15) * H1S + ch * 32 + quad * 8];
      #pragma unroll
      for (int nt = 0; nt < 2; ++nt) {
        bf16x8 b3f = *(const bf16x8*)&w3t[(size_t)(nt * 16 + l15) * 128 + ch * 32 + quad * 8];
        acc3[nt] = __builtin_amdgcn_mfma_f32_16x16x32_bf16(a3, b3f, acc3[nt], 0, 0, 0);
      }
    }
    #pragma unroll
    for (int nt = 0; nt < 2; ++nt) {
      int col = nt * 16 + l15;
      float bias = b3[col];
      #pragma unroll
      for (int rg = 0; rg < 4; ++rg) {
        int row = wave * 16 + quad * 4 + rg;
        s_kern[row * KS + col] = acc3[nt][rg] + bias;
      }
    }
  }
  __syncthreads();

  // ---------- fused reduce ----------
  {
    const int xloc = tid >> 5;
    const int c    = tid & 31;
    float acc[TDIM] = {0.f, 0.f, 0.f, 0.f};
    const int ebase = xloc * 8;
    #pragma unroll
    for (int j = 0; j < KNBR; ++j) {
      float kv = s_kern[(ebase + j) * KS + c];
      int idx = nidx[e0 + ebase + j];
      const float* fp = f_y + (size_t)idx * CDIM + c;
      #pragma unroll
      for (int t = 0; t < TDIM; ++t)
        acc[t] += kv * fp[(size_t)t * N_Y * CDIM];
    }
    const int xg = blockIdx.x * 8 + xloc;
    #pragma unroll
    for (int t = 0; t < TDIM; ++t)
      out[((size_t)t * N_X + xg) * CDIM + c] = acc[t];
  }
}

extern "C" void kernel_launch(void* const* d_in, const int* in_sizes, int n_in,
                              void* d_out, int out_size, void* d_ws, size_t ws_size,
                              hipStream_t stream)
{
  const float* y   = (const float*)d_in[0];
  const float* x   = (const float*)d_in[1];
  const float* f_y = (const float*)d_in[2];
  const int*  nidx = (const int*)d_in[3];
  const float* W0 = (const float*)d_in[4];  const float* b0 = (const float*)d_in[5];
  const float* W1 = (const float*)d_in[6];  const float* b1 = (const float*)d_in[7];
  const float* W2 = (const float*)d_in[8];  const float* b2 = (const float*)d_in[9];
  const float* W3 = (const float*)d_in[10]; const float* b3 = (const float*)d_in[11];

  char* ws = (char*)d_ws;
  short* c_y  = (short*)(ws + 0);           // 50000*128*2  = 12,800,000
  float* c_x  = (float*)(ws + 12800000);    // 32768*128*4  = 16,777,216
  short* w0yt = (short*)(ws + 29577216);    // 128*192*2 = 49,152
  short* w0xt = (short*)(ws + 29626368);    // 128*192*2 = 49,152
  short* w1t  = (short*)(ws + 29675520);    // 256*128*2 = 65,536
  short* w2t  = (short*)(ws + 29741056);    // 128*256*2 = 65,536
  short* w3t  = (short*)(ws + 29806592);    //  32*128*2 =  8,192

  hipLaunchKernelGGL(transpose_all, dim3((118784 + 255) / 256), dim3(256), 0, stream,
                     W0, W1, W2, W3, w0yt, w0xt, w1t, w2t, w3t);
  hipLaunchKernelGGL(precompute_c, dim3(782 + 512), dim3(256), 0, stream,
                     y, x, w0yt, w0xt, b0, c_y, c_x);
  hipLaunchKernelGGL(fused_edge, dim3(ECNT / 64), dim3(256), 0, stream,
                     c_y, c_x, nidx, f_y, w1t, b1, w2t, b2, w3t, b3, (float*)d_out);
}